// Round 15
// baseline (513.943 us; speedup 1.0000x reference)
//
#include <hip/hip_runtime.h>

#define NN 100000
#define EE 1600000
#define FF 128
#define SS 256
#define CC 32
#define KG 384     // gates GEMM K = F + S
#define NCOL 1024  // gates GEMM N = 4 gates * S
#define RBMAX 6249 // last 16-row block (NN/16 - 1)

typedef __attribute__((ext_vector_type(8))) short v8s;
typedef __attribute__((ext_vector_type(8))) unsigned short u8s;
typedef __attribute__((ext_vector_type(4))) float v4f;

__device__ __forceinline__ void gload_lds16(const void* g, void* l) {
  __builtin_amdgcn_global_load_lds(
      (const __attribute__((address_space(1))) void*)g,
      (__attribute__((address_space(3))) void*)l, 16, 0, 0);
}

__device__ __forceinline__ unsigned short f2bf(float f) {
  unsigned int u = __float_as_uint(f);
  u += 0x7FFF + ((u >> 16) & 1);  // RNE
  return (unsigned short)(u >> 16);
}
__device__ __forceinline__ float bf2f(unsigned short u) {
  return __uint_as_float(((unsigned int)u) << 16);
}
__device__ __forceinline__ float sigmoidf_(float x) { return 1.0f / (1.0f + __expf(-x)); }
__device__ __forceinline__ float tanhf_(float x) {
  float ax = fabsf(x);
  float e = __expf(2.0f * ax);
  float t = 1.0f - 2.0f / (e + 1.0f);
  return copysignf(t, x);
}

// ---------------- fused: degree atomics (bid<6250) + weight packs (bid>=6250) ----------------
// degcnt[d]: bits[0,40) = fixed-point (2^-24) sum of w, bits[40,64) = count.
// Returned old count = edge's position within d's CSR segment -> posA[e].
// Bf fragment-major (16x16x32): Bf[cb][ks][g][lc][e], lane = g*16+lc.
__global__ __launch_bounds__(256) void k_pre(
    const int* __restrict__ dst, const float* __restrict__ w,
    unsigned long long* __restrict__ degcnt, unsigned short* __restrict__ posA,
    const float* __restrict__ W1, unsigned short* __restrict__ W1T,
    const float* __restrict__ Wi, const float* __restrict__ Wf,
    const float* __restrict__ Wc, const float* __restrict__ Wo,
    const float* __restrict__ Ti, const float* __restrict__ Tf,
    const float* __restrict__ Tc, const float* __restrict__ To,
    unsigned short* __restrict__ Bf,
    const float* __restrict__ bci, const float* __restrict__ bcf,
    const float* __restrict__ bcc, const float* __restrict__ bco,
    const float* __restrict__ bii, const float* __restrict__ bif,
    const float* __restrict__ bic, const float* __restrict__ bio,
    float* __restrict__ biasP,
    const float* __restrict__ Wl, unsigned short* __restrict__ WlT) {
  const int bid0 = blockIdx.x, t = threadIdx.x;
  if (bid0 < 6250) {
    int e = bid0 * 256 + t;
    if (e < EE) {
      int d = dst[e];
      unsigned int wf = (unsigned int)__float2uint_rn(w[e] * 16777216.0f);
      unsigned long long v = (1ULL << 40) | (unsigned long long)wf;
      unsigned long long old = atomicAdd(&degcnt[d], v);
      posA[e] = (unsigned short)(old >> 40);
    }
    return;
  }
  const int bid = bid0 - 6250;
  if (bid < 1536) {
    // coalesced read mapping: k = i>>10 (uniform per 1024), col = i&1023
    int i = bid * 256 + t;  // over 384*1024
    int k = i >> 10, col = i & 1023;
    int th = col >> 6, rem = col & 63, g8 = rem >> 4, slo = rem & 15;
    int s = th * 16 + slo;
    const float* Wp = (g8 == 0) ? Wi : (g8 == 1) ? Wf : (g8 == 2) ? Wc : Wo;
    const float* Tp = (g8 == 0) ? Ti : (g8 == 1) ? Tf : (g8 == 2) ? Tc : To;
    float v = (k < FF) ? Wp[(size_t)k * SS + s] : Tp[(size_t)(k - FF) * SS + s];
    int cb = col >> 4, lc = col & 15, ks = k >> 5, g = (k & 31) >> 3, e = k & 7;
    Bf[(((size_t)cb * 12 + ks) * 512) + g * 128 + lc * 8 + e] = f2bf(v);
  } else if (bid < 1600) {
    int i = (bid - 1536) * 256 + t;  // over 128*128
    if (i < FF * FF) {
      int col = i >> 7, k = i & 127;
      W1T[i] = f2bf(W1[k * FF + col]);
    }
  } else if (bid < 1604) {
    int col = (bid - 1600) * 256 + t;
    if (col < NCOL) {
      int th = col >> 6, rem = col & 63, g = rem >> 4, slo = rem & 15;
      int s = th * 16 + slo;
      const float* P = (g == 0) ? bci : (g == 1) ? bcf : (g == 2) ? bcc : bco;
      const float* Q = (g == 0) ? bii : (g == 1) ? bif : (g == 2) ? bic : bio;
      biasP[col] = P[s] + Q[s];
    }
  } else {
    int i = (bid - 1604) * 256 + t;  // over 32*256
    if (i < CC * SS) {
      int c = i >> 8, k = i & 255;
      WlT[i] = f2bf(Wl[(size_t)k * CC + c]);
    }
  }
}

// ---------------- CSR build: scan (fused dinv + cnt unpack) ----------------
__global__ __launch_bounds__(256) void k_scan1(const unsigned long long* __restrict__ degcnt,
                                               int* __restrict__ loc, int* __restrict__ cnt32,
                                               int* __restrict__ blkSum, float* __restrict__ dinv) {
  __shared__ int s[256];
  int i = blockIdx.x * 256 + threadIdx.x;
  int v = 0;
  if (i < NN) {
    unsigned long long p = degcnt[i];
    v = (int)(p >> 40);
    float dw = (float)(p & ((1ULL << 40) - 1)) * (1.0f / 16777216.0f);
    dinv[i] = rsqrtf(dw + 1.0f);  // self-loop folded, >=1
    cnt32[i] = v;
  }
  s[threadIdx.x] = v;
  __syncthreads();
#pragma unroll
  for (int d = 1; d < 256; d <<= 1) {
    int t = (threadIdx.x >= d) ? s[threadIdx.x - d] : 0;
    __syncthreads();
    s[threadIdx.x] += t;
    __syncthreads();
  }
  if (i < NN) loc[i] = s[threadIdx.x] - v;  // block-local exclusive
  if (threadIdx.x == 255) blkSum[blockIdx.x] = s[255];
}
__global__ __launch_bounds__(512) void k_scan2(int* __restrict__ blkSum, int* __restrict__ blkOff, int nb) {
  __shared__ int s[512];
  int v = (threadIdx.x < nb) ? blkSum[threadIdx.x] : 0;
  s[threadIdx.x] = v;
  __syncthreads();
#pragma unroll
  for (int d = 1; d < 512; d <<= 1) {
    int t = (threadIdx.x >= d) ? s[threadIdx.x - d] : 0;
    __syncthreads();
    s[threadIdx.x] += t;
    __syncthreads();
  }
  if (threadIdx.x < nb) blkOff[threadIdx.x] = s[threadIdx.x] - v;  // exclusive
}

// ---------------- fused: CSR fill (no atomics, bid<6250) + GEMM1 (bid>=6250) ----------------
// epack[pos] (4B): bits[15,32) = src (<2^17), bits[0,15) = bf16(coef) (sign always 0).
__global__ __launch_bounds__(256) void k_mid(
    const int* __restrict__ src, const int* __restrict__ dst,
    const float* __restrict__ w, const float* __restrict__ dinv,
    const int* __restrict__ loc, const int* __restrict__ blkOff,
    const unsigned short* __restrict__ posA, unsigned int* __restrict__ epack,
    const float* __restrict__ x, const unsigned short* __restrict__ BT,
    unsigned short* __restrict__ Cout) {
  __shared__ unsigned short As[128 * 128];
  const int bid0 = blockIdx.x;
  const int t = threadIdx.x;
  if (bid0 < 6250) {
    int e = bid0 * 256 + t;
    if (e < EE) {
      int s = src[e], d = dst[e];
      int pos = loc[d] + blkOff[d >> 8] + (int)posA[e];
      float coef = dinv[s] * w[e] * dinv[d];
      epack[pos] = ((unsigned int)s << 15) | (unsigned int)f2bf(coef);
    }
    return;
  }
  // ---- GEMM1: xw = f2bf(x) @ W1, fused fp32->bf16 pack ----
  const int wave = t >> 6, lane = t & 63;
  const int wr = wave >> 1, wc = wave & 1;
  const int l15 = lane & 15, l4 = lane >> 4;
  const int row0 = (bid0 - 6250) * 128;
  {
    const int rr = t >> 4, c8 = t & 15;
#pragma unroll
    for (int c = 0; c < 8; ++c) {
      int row = c * 16 + rr;
      int ar = row0 + row; if (ar >= NN) ar = NN - 1;
      const float* xp = x + (size_t)ar * 128 + c8 * 8;
      v4f f0 = *(const v4f*)(xp);
      v4f f1 = *(const v4f*)(xp + 4);
      u8s u;
      u[0] = f2bf(f0.x); u[1] = f2bf(f0.y); u[2] = f2bf(f0.z); u[3] = f2bf(f0.w);
      u[4] = f2bf(f1.x); u[5] = f2bf(f1.y); u[6] = f2bf(f1.z); u[7] = f2bf(f1.w);
      int sc = c8 ^ (row & 7);
      *(u8s*)&As[row * 128 + sc * 8] = u;
    }
  }
  __syncthreads();
  v4f acc[4][4];
  v4f zero = {0.f, 0.f, 0.f, 0.f};
#pragma unroll
  for (int m = 0; m < 4; ++m)
#pragma unroll
    for (int n = 0; n < 4; ++n) acc[m][n] = zero;
#pragma unroll
  for (int kt = 0; kt < 4; ++kt) {
    v8s a[4], b[4];
#pragma unroll
    for (int m = 0; m < 4; ++m) {
      int row = wr * 64 + m * 16 + l15;
      int j8 = kt * 4 + l4;
      a[m] = *(const v8s*)&As[row * 128 + ((j8 ^ (row & 7)) * 8)];
    }
#pragma unroll
    for (int n = 0; n < 4; ++n)
      b[n] = *(const v8s*)&BT[(size_t)(wc * 64 + n * 16 + l15) * 128 + kt * 32 + l4 * 8];
#pragma unroll
    for (int m = 0; m < 4; ++m)
#pragma unroll
      for (int n = 0; n < 4; ++n)
        acc[m][n] = __builtin_amdgcn_mfma_f32_16x16x32_bf16(a[m], b[n], acc[m][n], 0, 0, 0);
  }
#pragma unroll
  for (int m = 0; m < 4; ++m) {
#pragma unroll
    for (int r = 0; r < 4; ++r) {
      int row = row0 + wr * 64 + m * 16 + l4 * 4 + r;
      if (row < NN) {
#pragma unroll
        for (int n = 0; n < 4; ++n)
          Cout[(size_t)row * 128 + wc * 64 + n * 16 + l15] = f2bf(acc[m][n][r]);
      }
    }
  }
}

// ---------------- CSR gather (SpMM) + fused H0 pack -> fragment-major A2f ----------------
// element (row n, col c): rb=n>>4, ks=c>>5, g=(c&31)>>3, e=c&7, lane=g*16+(n&15)
// A2f index (ushort) = rb*6144 + ks*512 + g*128 + (n&15)*8 + e
__global__ __launch_bounds__(256) void k_gather(const unsigned short* __restrict__ xwb,
                                                const unsigned int* __restrict__ epack,
                                                const int* __restrict__ loc, const int* __restrict__ blkOff,
                                                const int* __restrict__ cnt,
                                                const float* __restrict__ dinv, const float* __restrict__ b1,
                                                const float* __restrict__ H0,
                                                unsigned short* __restrict__ A2f) {
  const int wave = threadIdx.x >> 6, lane = threadIdx.x & 63;
  const int n = blockIdx.x * 4 + wave;  // NN divisible by 4
  const int half = lane >> 5, l32 = lane & 31;
  const int c0 = l32 * 4;               // 4 cols per lane, 32 lanes cover the row
  const int base = __builtin_amdgcn_readfirstlane(loc[n] + blkOff[n >> 8]);
  const int len = __builtin_amdgcn_readfirstlane(cnt[n]);
  const size_t rbase = (size_t)(n >> 4) * 6144;
  const int r8 = (n & 15) * 8;
  float a0 = 0.f, a1 = 0.f, a2 = 0.f, a3 = 0.f;
  if (half == 0) {
    float di = dinv[n];
    float slf = di * di;
    ushort4 xv = *(const ushort4*)(xwb + (size_t)n * 128 + c0);
    a0 = b1[c0]     + slf * bf2f(xv.x);
    a1 = b1[c0 + 1] + slf * bf2f(xv.y);
    a2 = b1[c0 + 2] + slf * bf2f(xv.z);
    a3 = b1[c0 + 3] + slf * bf2f(xv.w);
  }
  float p0 = 0.f, p1 = 0.f, p2 = 0.f, p3 = 0.f;
  float q0 = 0.f, q1 = 0.f, q2 = 0.f, q3 = 0.f;
  float r0 = 0.f, r1 = 0.f, r2 = 0.f, r3 = 0.f;
  const int pairs = len >> 1;
  int j = 0;
  for (; j + 4 <= pairs; j += 4) {   // 8 edges per iteration (4 per half-wave)
    unsigned int m0 = epack[base + 2 * j + half];
    unsigned int m1 = epack[base + 2 * j + 2 + half];
    unsigned int m2 = epack[base + 2 * j + 4 + half];
    unsigned int m3 = epack[base + 2 * j + 6 + half];
    ushort4 v0 = *(const ushort4*)(xwb + (size_t)(m0 >> 15) * 128 + c0);
    ushort4 v1 = *(const ushort4*)(xwb + (size_t)(m1 >> 15) * 128 + c0);
    ushort4 v2 = *(const ushort4*)(xwb + (size_t)(m2 >> 15) * 128 + c0);
    ushort4 v3 = *(const ushort4*)(xwb + (size_t)(m3 >> 15) * 128 + c0);
    float cf0 = __uint_as_float((m0 & 0x7FFFu) << 16);
    float cf1 = __uint_as_float((m1 & 0x7FFFu) << 16);
    float cf2 = __uint_as_float((m2 & 0x7FFFu) << 16);
    float cf3 = __uint_as_float((m3 & 0x7FFFu) << 16);
    a0 += cf0 * bf2f(v0.x); a1 += cf0 * bf2f(v0.y);
    a2 += cf0 * bf2f(v0.z); a3 += cf0 * bf2f(v0.w);
    p0 += cf1 * bf2f(v1.x); p1 += cf1 * bf2f(v1.y);
    p2 += cf1 * bf2f(v1.z); p3 += cf1 * bf2f(v1.w);
    q0 += cf2 * bf2f(v2.x); q1 += cf2 * bf2f(v2.y);
    q2 += cf2 * bf2f(v2.z); q3 += cf2 * bf2f(v2.w);
    r0 += cf3 * bf2f(v3.x); r1 += cf3 * bf2f(v3.y);
    r2 += cf3 * bf2f(v3.z); r3 += cf3 * bf2f(v3.w);
  }
  for (; j < pairs; ++j) {
    unsigned int m0 = epack[base + 2 * j + half];
    ushort4 v0 = *(const ushort4*)(xwb + (size_t)(m0 >> 15) * 128 + c0);
    float cf0 = __uint_as_float((m0 & 0x7FFFu) << 16);
    a0 += cf0 * bf2f(v0.x); a1 += cf0 * bf2f(v0.y);
    a2 += cf0 * bf2f(v0.z); a3 += cf0 * bf2f(v0.w);
  }
  if ((len & 1) && half == 0) {      // odd tail edge
    unsigned int m0 = epack[base + len - 1];
    ushort4 v0 = *(const ushort4*)(xwb + (size_t)(m0 >> 15) * 128 + c0);
    float cf0 = __uint_as_float((m0 & 0x7FFFu) << 16);
    a0 += cf0 * bf2f(v0.x); a1 += cf0 * bf2f(v0.y);
    a2 += cf0 * bf2f(v0.z); a3 += cf0 * bf2f(v0.w);
  }
  a0 += (p0 + q0) + r0; a1 += (p1 + q1) + r1;
  a2 += (p2 + q2) + r2; a3 += (p3 + q3) + r3;
  a0 += __shfl_xor(a0, 32, 64);
  a1 += __shfl_xor(a1, 32, 64);
  a2 += __shfl_xor(a2, 32, 64);
  a3 += __shfl_xor(a3, 32, 64);
  if (half == 0) {
    int ks = c0 >> 5, g = (c0 & 31) >> 3, e = c0 & 7;  // e in {0,4}
    ushort4 o; o.x = f2bf(a0); o.y = f2bf(a1); o.z = f2bf(a2); o.w = f2bf(a3);
    *(ushort4*)(A2f + rbase + (size_t)ks * 512 + g * 128 + r8 + e) = o;
  }
  // fused: H0 f32 -> bf16 into cols [128,384)
  {
    int c = 128 + lane * 4;
    v4f hv = *(const v4f*)(H0 + (size_t)n * 256 + lane * 4);
    ushort4 ho; ho.x = f2bf(hv.x); ho.y = f2bf(hv.y); ho.z = f2bf(hv.z); ho.w = f2bf(hv.w);
    int ks = c >> 5, g = (c & 31) >> 3, e = c & 7;
    *(ushort4*)(A2f + rbase + (size_t)ks * 512 + g * 128 + r8 + e) = ho;
  }
}

// ---------------- gates GEMM + fused LSTM epilogue ----------------
// NO LDS, NO BARRIERS: fragment-major A2f/Bf, every load = base+lane*16B (1KB coalesced).
// Named even/odd register double-buffer (a0/b0 <-> a1/b1) forces 8 loads in flight under
// each 16-MFMA cluster; free-running waves + setprio. XCD-chunked, y-fastest (A L2 reuse).
__global__ __launch_bounds__(256, 3) void k_gates(const unsigned short* __restrict__ A2f,
                                                  const unsigned short* __restrict__ Bf,
                                                  const float* __restrict__ biasP, const float* __restrict__ C0,
                                                  float* __restrict__ Hn, float* __restrict__ Cn,
                                                  unsigned short* __restrict__ hrelu) {
  const int g = blockIdx.x;
  const int xcd = g & 7, li = g >> 3;
  const int xl = li >> 3, y = li & 7;   // per-XCD: y fastest -> A-panel L2 reuse
  const int xb = xcd * 98 + xl;
  if (xb >= 782) return;
  const int t = threadIdx.x;
  const int wave = t >> 6, lane = t & 63;
  const int wr = wave >> 1, wc = wave & 1;
  const int l15 = lane & 15, l4 = lane >> 4;
  const int row0 = xb * 128;

  const unsigned short* ap[4];
#pragma unroll
  for (int m = 0; m < 4; ++m) {
    int rb = xb * 8 + wr * 4 + m;
    if (rb > RBMAX) rb = RBMAX;  // clamped rows computed but never stored
    ap[m] = A2f + (size_t)rb * 6144 + lane * 8;
  }
  const unsigned short* bp[4];
#pragma unroll
  for (int n = 0; n < 4; ++n) {
    int cb = y * 8 + wc * 4 + n;
    bp[n] = Bf + (size_t)cb * 6144 + lane * 8;
  }

  v4f acc[4][4];
  v4f zero = {0.f, 0.f, 0.f, 0.f};
#pragma unroll
  for (int m = 0; m < 4; ++m)
#pragma unroll
    for (int n = 0; n < 4; ++n) acc[m][n] = zero;

#define LOADF(adst, bdst, ks)                                                   \
  {                                                                             \
    _Pragma("unroll") for (int m = 0; m < 4; ++m)                               \
      adst[m] = *(const v8s*)(ap[m] + (ks) * 512);                              \
    _Pragma("unroll") for (int n = 0; n < 4; ++n)                               \
      bdst[n] = *(const v8s*)(bp[n] + (ks) * 512);                              \
  }
#define MFMA16(aa, bb)                                                          \
  {                                                                             \
    __builtin_amdgcn_s_setprio(1);                                              \
    _Pragma("unroll") for (int m = 0; m < 4; ++m)                               \
      _Pragma("unroll") for (int n = 0; n < 4; ++n)                             \
        acc[m][n] = __builtin_amdgcn_mfma_f32_16x16x32_bf16(aa[m], bb[n], acc[m][n], 0, 0, 0); \
    __builtin_amdgcn_s_setprio(0);                                              \
  }

  v8s aE[4], bE[4], aO[4], bO[4];
  LOADF(aE, bE, 0);
#pragma unroll
  for (int kt = 0; kt < 12; kt += 2) {
    if (kt + 1 < 12) LOADF(aO, bO, kt + 1);
    __builtin_amdgcn_sched_barrier(0);
    MFMA16(aE, bE);
    if (kt + 2 < 12) LOADF(aE, bE, kt + 2);
    __builtin_amdgcn_sched_barrier(0);
    MFMA16(aO, bO);
  }
#undef LOADF
#undef MFMA16

  // epilogue: n-frag index == gate (0:i 1:f 2:c 3:o), s = (2*y+wc)*16 + l15
  const int s = (2 * y + wc) * 16 + l15;
  const int cb = y * 128 + wc * 64 + l15;
  float bi = biasP[cb], bfv = biasP[cb + 16], bcv = biasP[cb + 32], bov = biasP[cb + 48];
#pragma unroll
  for (int m = 0; m < 4; ++m) {
#pragma unroll
    for (int r = 0; r < 4; ++r) {
      int row = row0 + wr * 64 + m * 16 + l4 * 4 + r;
      if (row < NN) {
        float I  = sigmoidf_(acc[m][0][r] + bi);
        float Fg = sigmoidf_(acc[m][1][r] + bfv);
        float T  = tanhf_(acc[m][2][r] + bcv);
        float O  = sigmoidf_(acc[m][3][r] + bov);
        size_t idx = (size_t)row * SS + s;
        float c0 = C0[idx];
        float cn = Fg * c0 + I * T;
        float hn = O * tanhf_(cn);
        Cn[idx] = cn;
        Hn[idx] = hn;
        hrelu[idx] = f2bf(hn > 0.f ? hn : 0.f);
      }
    }
  }
}

// ---------------- output linear + fused softmax ----------------
__global__ __launch_bounds__(256) void k_linsoft(const unsigned short* __restrict__ Arelu,
                                                 const unsigned short* __restrict__ WlT,
                                                 const float* __restrict__ bl, float* __restrict__ out) {
  __shared__ unsigned short As[128 * 256];
  const int t = threadIdx.x;
  const int wave = t >> 6, lane = t & 63;
  const int l15 = lane & 15, l4 = lane >> 4;
  const int row0 = blockIdx.x * 128;
#pragma unroll
  for (int c = 0; c < 16; ++c) {
    int slot = c * 256 + t;
    int row = slot >> 5, chunk = slot & 31;
    int ar = row0 + row; if (ar >= NN) ar = NN - 1;
    int sc = chunk ^ (row & 7);
    gload_lds16(Arelu + (size_t)ar * 256 + sc * 8, &As[row * 256 + chunk * 8]);
  }
  v8s bfr[8][2];
#pragma unroll
  for (int ks = 0; ks < 8; ++ks)
#pragma unroll
    for (int n = 0; n < 2; ++n)
      bfr[ks][n] = *(const v8s*)&WlT[(size_t)(n * 16 + l15) * 256 + ks * 32 + l4 * 8];
  v4f acc[2][2];
  v4f zero = {0.f, 0.f, 0.f, 0.f};
#pragma unroll
  for (int m = 0; m < 2; ++m)
#pragma unroll
    for (int n = 0; n < 2; ++n) acc[m][n] = zero;
  __syncthreads();
#pragma unroll
  for (int ks = 0; ks < 8; ++ks) {
    v8s a[2];
#pragma unroll
    for (int m = 0; m < 2; ++m) {
      int row = wave * 32 + m * 16 + l15;
      int j8 = ks * 4 + l4;
      a[m] = *(const v8s*)&As[row * 256 + ((j8 ^ (row & 7)) * 8)];
    }
#pragma unroll
    for (int m = 0; m < 2; ++m)
#pragma unroll
      for (int n = 0; n < 2; ++n)
        acc[m][n] = __builtin_amdgcn_mfma_f32_16x16x32_bf16(a[m], bfr[ks][n], acc[m][n], 0, 0, 0);
  }
  float b0 = bl[l15], b1v = bl[16 + l15];
#pragma unroll
  for (int m = 0; m < 2; ++m) {
#pragma unroll
    for (int r = 0; r < 4; ++r) {
      int row = row0 + wave * 32 + m * 16 + l4 * 4 + r;
      float v0 = acc[m][0][r] + b0;
      float v1 = acc[m][1][r] + b1v;
      float mx = fmaxf(v0, v1);
#pragma unroll
      for (int d = 1; d < 16; d <<= 1) mx = fmaxf(mx, __shfl_xor(mx, d, 64));
      float e0 = __expf(v0 - mx), e1 = __expf(v1 - mx);
      float sm = e0 + e1;
#pragma unroll
      for (int d = 1; d < 16; d <<= 1) sm += __shfl_xor(sm, d, 64);
      if (row < NN) {
        out[(size_t)row * 32 + l15] = e0 / sm;
        out[(size_t)row * 32 + 16 + l15] = e1 / sm;
      }
    }
  }
}

extern "C" void kernel_launch(void* const* d_in, const int* in_sizes, int n_in,
                              void* d_out, int out_size, void* d_ws, size_t ws_size,
                              hipStream_t stream) {
  (void)in_sizes; (void)n_in; (void)out_size; (void)ws_size;
  const float* x   = (const float*)d_in[0];
  const int*   ei  = (const int*)d_in[1];
  const float* ew  = (const float*)d_in[2];
  const float* H0  = (const float*)d_in[3];
  const float* C0  = (const float*)d_in[4];
  const float* W1  = (const float*)d_in[5];
  const float* b1  = (const float*)d_in[6];
  const float* Wi  = (const float*)d_in[7];
  const float* Ti  = (const float*)d_in[8];
  const float* bci = (const float*)d_in[9];
  const float* bii = (const float*)d_in[10];
  const float* Wf  = (const float*)d_in[11];
  const float* Tf  = (const float*)d_in[12];
  const float* bcf = (const float*)d_in[13];
  const float* bif = (const float*)d_in[14];
  const float* Wc  = (const float*)d_in[15];
  const float* Tc  = (const float*)d_in[16];
  const float* bcc = (const float*)d_in[17];
  const float* bic = (const float*)d_in[18];
  const float* Wo  = (const float*)d_in[19];
  const float* To  = (const float*)d_in[20];
  const float* bco = (const float*)d_in[21];
  const float* bio = (const float*)d_in[22];
  const float* Wl  = (const float*)d_in[23];
  const float* bl  = (const float*)d_in[24];

  const int* srcI = ei;
  const int* dstI = ei + EE;

  char* ws = (char*)d_ws;
  size_t off = 0;
  auto carve = [&](size_t bytes) -> char* {
    char* p = ws + off;
    off += (bytes + 255) & ~(size_t)255;
    return p;
  };
  unsigned long long* degcnt = (unsigned long long*)carve((size_t)NN * 8);
  float* dinv          = (float*)carve((size_t)NN * 4);
  int*   loc           = (int*)carve((size_t)NN * 4);
  int*   cnt32         = (int*)carve((size_t)NN * 4);
  int*   blkSum        = (int*)carve(512 * 4);
  int*   blkOff        = (int*)carve(512 * 4);
  unsigned short* posA = (unsigned short*)carve((size_t)EE * 2);
  unsigned int* epack  = (unsigned int*)carve((size_t)EE * 4);
  unsigned short* W1T  = (unsigned short*)carve((size_t)FF * FF * 2);
  unsigned short* xwb  = (unsigned short*)carve((size_t)NN * FF * 2);
  unsigned short* A2f  = (unsigned short*)carve((size_t)6250 * 6144 * 2);
  unsigned short* Bf   = (unsigned short*)carve((size_t)64 * 6144 * 2);
  float* biasP         = (float*)carve((size_t)NCOL * 4);
  unsigned short* WlT  = (unsigned short*)carve((size_t)CC * SS * 2);
  unsigned short* hrelu = (unsigned short*)carve((size_t)NN * SS * 2);

  float* outSm = (float*)d_out;
  float* HnO = outSm + (size_t)NN * CC;
  float* CnO = HnO + (size_t)NN * SS;

  const int NB = (NN + 255) / 256;  // 391

  hipMemsetAsync(degcnt, 0, (size_t)NN * 8, stream);
  // fused: degree atomics + all weight packs
  k_pre<<<6250 + 1636, 256, 0, stream>>>(dstI, ew, degcnt, posA,
                                         W1, W1T, Wi, Wf, Wc, Wo, Ti, Tf, Tc, To, Bf,
                                         bci, bcf, bcc, bco, bii, bif, bic, bio, biasP,
                                         Wl, WlT);
  k_scan1<<<NB, 256, 0, stream>>>(degcnt, loc, cnt32, blkSum, dinv);
  k_scan2<<<1, 512, 0, stream>>>(blkSum, blkOff, NB);
  // fused: CSR fill + GEMM1
  k_mid<<<6250 + 782, 256, 0, stream>>>(srcI, dstI, ew, dinv, loc, blkOff, posA, epack,
                                        x, W1T, xwb);
  k_gather<<<25000, 256, 0, stream>>>(xwb, epack, loc, blkOff, cnt32, dinv, b1, H0, A2f);
  k_gates<<<6272, 256, 0, stream>>>(A2f, Bf, biasP, C0, HnO, CnO, hrelu);
  k_linsoft<<<782, 256, 0, stream>>>(hrelu, WlT, bl, outSm);
}

// Round 16
// 474.780 us; speedup vs baseline: 1.0825x; 1.0825x over previous
//
#include <hip/hip_runtime.h>

#define NN 100000
#define EE 1600000
#define FF 128
#define SS 256
#define CC 32
#define KG 384     // gates GEMM K = F + S
#define NCOL 1024  // gates GEMM N = 4 gates * S

typedef __attribute__((ext_vector_type(8))) short v8s;
typedef __attribute__((ext_vector_type(8))) unsigned short u8s;
typedef __attribute__((ext_vector_type(4))) float v4f;

__device__ __forceinline__ void gload_lds16(const void* g, void* l) {
  __builtin_amdgcn_global_load_lds(
      (const __attribute__((address_space(1))) void*)g,
      (__attribute__((address_space(3))) void*)l, 16, 0, 0);
}

__device__ __forceinline__ unsigned short f2bf(float f) {
  unsigned int u = __float_as_uint(f);
  u += 0x7FFF + ((u >> 16) & 1);  // RNE
  return (unsigned short)(u >> 16);
}
__device__ __forceinline__ float bf2f(unsigned short u) {
  return __uint_as_float(((unsigned int)u) << 16);
}
__device__ __forceinline__ float sigmoidf_(float x) { return 1.0f / (1.0f + __expf(-x)); }
__device__ __forceinline__ float tanhf_(float x) {
  float ax = fabsf(x);
  float e = __expf(2.0f * ax);
  float t = 1.0f - 2.0f / (e + 1.0f);
  return copysignf(t, x);
}

// ---------------- fused: degree atomics (bid<6250) + weight packs (bid>=6250) ----------------
// degcnt[d]: bits[0,40) = fixed-point (2^-24) sum of w, bits[40,64) = count.
// Returned old count = edge's position within d's CSR segment -> posA[e].
__global__ __launch_bounds__(256) void k_pre(
    const int* __restrict__ dst, const float* __restrict__ w,
    unsigned long long* __restrict__ degcnt, unsigned short* __restrict__ posA,
    const float* __restrict__ W1, unsigned short* __restrict__ W1T,
    const float* __restrict__ Wi, const float* __restrict__ Wf,
    const float* __restrict__ Wc, const float* __restrict__ Wo,
    const float* __restrict__ Ti, const float* __restrict__ Tf,
    const float* __restrict__ Tc, const float* __restrict__ To,
    unsigned short* __restrict__ BTk,
    const float* __restrict__ bci, const float* __restrict__ bcf,
    const float* __restrict__ bcc, const float* __restrict__ bco,
    const float* __restrict__ bii, const float* __restrict__ bif,
    const float* __restrict__ bic, const float* __restrict__ bio,
    float* __restrict__ biasP,
    const float* __restrict__ Wl, unsigned short* __restrict__ WlT) {
  const int bid0 = blockIdx.x, t = threadIdx.x;
  if (bid0 < 6250) {
    int e = bid0 * 256 + t;
    if (e < EE) {
      int d = dst[e];
      unsigned int wf = (unsigned int)__float2uint_rn(w[e] * 16777216.0f);
      unsigned long long v = (1ULL << 40) | (unsigned long long)wf;
      unsigned long long old = atomicAdd(&degcnt[d], v);
      posA[e] = (unsigned short)(old >> 40);
    }
    return;
  }
  const int bid = bid0 - 6250;
  if (bid < 1536) {
    // coalesced mapping: k = i>>10 (uniform per 1024), col = i&1023 -> 64B-contig W reads
    int i = bid * 256 + t;  // over 384*1024
    int k = i >> 10, col = i & 1023;
    int th = col >> 6, rem = col & 63, g = rem >> 4, slo = rem & 15;
    int s = th * 16 + slo;
    const float* Wp = (g == 0) ? Wi : (g == 1) ? Wf : (g == 2) ? Wc : Wo;
    const float* Tp = (g == 0) ? Ti : (g == 1) ? Tf : (g == 2) ? Tc : To;
    float v = (k < FF) ? Wp[(size_t)k * SS + s] : Tp[(size_t)(k - FF) * SS + s];
    int p = k >> 3, j = k & 7;
    BTk[((size_t)p * NCOL + col) * 8 + j] = f2bf(v);
  } else if (bid < 1600) {
    int i = (bid - 1536) * 256 + t;  // over 128*128
    if (i < FF * FF) {
      int col = i >> 7, k = i & 127;
      W1T[i] = f2bf(W1[k * FF + col]);
    }
  } else if (bid < 1604) {
    int col = (bid - 1600) * 256 + t;
    if (col < NCOL) {
      int th = col >> 6, rem = col & 63, g = rem >> 4, slo = rem & 15;
      int s = th * 16 + slo;
      const float* P = (g == 0) ? bci : (g == 1) ? bcf : (g == 2) ? bcc : bco;
      const float* Q = (g == 0) ? bii : (g == 1) ? bif : (g == 2) ? bic : bio;
      biasP[col] = P[s] + Q[s];
    }
  } else {
    int i = (bid - 1604) * 256 + t;  // over 32*256
    if (i < CC * SS) {
      int c = i >> 8, k = i & 255;
      WlT[i] = f2bf(Wl[(size_t)k * CC + c]);
    }
  }
}

// ---------------- CSR build: scan (fused dinv + cnt unpack) ----------------
__global__ __launch_bounds__(256) void k_scan1(const unsigned long long* __restrict__ degcnt,
                                               int* __restrict__ loc, int* __restrict__ cnt32,
                                               int* __restrict__ blkSum, float* __restrict__ dinv) {
  __shared__ int s[256];
  int i = blockIdx.x * 256 + threadIdx.x;
  int v = 0;
  if (i < NN) {
    unsigned long long p = degcnt[i];
    v = (int)(p >> 40);
    float dw = (float)(p & ((1ULL << 40) - 1)) * (1.0f / 16777216.0f);
    dinv[i] = rsqrtf(dw + 1.0f);  // self-loop folded, >=1
    cnt32[i] = v;
  }
  s[threadIdx.x] = v;
  __syncthreads();
#pragma unroll
  for (int d = 1; d < 256; d <<= 1) {
    int t = (threadIdx.x >= d) ? s[threadIdx.x - d] : 0;
    __syncthreads();
    s[threadIdx.x] += t;
    __syncthreads();
  }
  if (i < NN) loc[i] = s[threadIdx.x] - v;  // block-local exclusive
  if (threadIdx.x == 255) blkSum[blockIdx.x] = s[255];
}
__global__ __launch_bounds__(512) void k_scan2(int* __restrict__ blkSum, int* __restrict__ blkOff, int nb) {
  __shared__ int s[512];
  int v = (threadIdx.x < nb) ? blkSum[threadIdx.x] : 0;
  s[threadIdx.x] = v;
  __syncthreads();
#pragma unroll
  for (int d = 1; d < 512; d <<= 1) {
    int t = (threadIdx.x >= d) ? s[threadIdx.x - d] : 0;
    __syncthreads();
    s[threadIdx.x] += t;
    __syncthreads();
  }
  if (threadIdx.x < nb) blkOff[threadIdx.x] = s[threadIdx.x] - v;  // exclusive
}

// ---------------- fused: CSR fill (no atomics, bid<6250) + GEMM1 (bid>=6250) ----------------
// epack[pos] (4B): bits[15,32) = src (<2^17), bits[0,15) = bf16(coef) (sign always 0).
__global__ __launch_bounds__(256) void k_mid(
    const int* __restrict__ src, const int* __restrict__ dst,
    const float* __restrict__ w, const float* __restrict__ dinv,
    const int* __restrict__ loc, const int* __restrict__ blkOff,
    const unsigned short* __restrict__ posA, unsigned int* __restrict__ epack,
    const float* __restrict__ x, const unsigned short* __restrict__ BT,
    unsigned short* __restrict__ Cout) {
  __shared__ unsigned short As[128 * 128];
  const int bid0 = blockIdx.x;
  const int t = threadIdx.x;
  if (bid0 < 6250) {
    int e = bid0 * 256 + t;
    if (e < EE) {
      int s = src[e], d = dst[e];
      int pos = loc[d] + blkOff[d >> 8] + (int)posA[e];
      float coef = dinv[s] * w[e] * dinv[d];
      epack[pos] = ((unsigned int)s << 15) | (unsigned int)f2bf(coef);
    }
    return;
  }
  // ---- GEMM1: xw = f2bf(x) @ W1, fused fp32->bf16 pack ----
  const int wave = t >> 6, lane = t & 63;
  const int wr = wave >> 1, wc = wave & 1;
  const int l15 = lane & 15, l4 = lane >> 4;
  const int row0 = (bid0 - 6250) * 128;
  {
    const int rr = t >> 4, c8 = t & 15;
#pragma unroll
    for (int c = 0; c < 8; ++c) {
      int row = c * 16 + rr;
      int ar = row0 + row; if (ar >= NN) ar = NN - 1;
      const float* xp = x + (size_t)ar * 128 + c8 * 8;
      v4f f0 = *(const v4f*)(xp);
      v4f f1 = *(const v4f*)(xp + 4);
      u8s u;
      u[0] = f2bf(f0.x); u[1] = f2bf(f0.y); u[2] = f2bf(f0.z); u[3] = f2bf(f0.w);
      u[4] = f2bf(f1.x); u[5] = f2bf(f1.y); u[6] = f2bf(f1.z); u[7] = f2bf(f1.w);
      int sc = c8 ^ (row & 7);
      *(u8s*)&As[row * 128 + sc * 8] = u;
    }
  }
  __syncthreads();
  v4f acc[4][4];
  v4f zero = {0.f, 0.f, 0.f, 0.f};
#pragma unroll
  for (int m = 0; m < 4; ++m)
#pragma unroll
    for (int n = 0; n < 4; ++n) acc[m][n] = zero;
#pragma unroll
  for (int kt = 0; kt < 4; ++kt) {
    v8s a[4], b[4];
#pragma unroll
    for (int m = 0; m < 4; ++m) {
      int row = wr * 64 + m * 16 + l15;
      int j8 = kt * 4 + l4;
      a[m] = *(const v8s*)&As[row * 128 + ((j8 ^ (row & 7)) * 8)];
    }
#pragma unroll
    for (int n = 0; n < 4; ++n)
      b[n] = *(const v8s*)&BT[(size_t)(wc * 64 + n * 16 + l15) * 128 + kt * 32 + l4 * 8];
#pragma unroll
    for (int m = 0; m < 4; ++m)
#pragma unroll
      for (int n = 0; n < 4; ++n)
        acc[m][n] = __builtin_amdgcn_mfma_f32_16x16x32_bf16(a[m], b[n], acc[m][n], 0, 0, 0);
  }
#pragma unroll
  for (int m = 0; m < 4; ++m) {
#pragma unroll
    for (int r = 0; r < 4; ++r) {
      int row = row0 + wr * 64 + m * 16 + l4 * 4 + r;
      if (row < NN) {
#pragma unroll
        for (int n = 0; n < 4; ++n)
          Cout[(size_t)row * 128 + wc * 64 + n * 16 + l15] = f2bf(acc[m][n][r]);
      }
    }
  }
}

// ---------------- CSR gather (SpMM) + fused H0 pack: 8 edges in flight per wave ----------------
__global__ __launch_bounds__(256) void k_gather(const unsigned short* __restrict__ xwb,
                                                const unsigned int* __restrict__ epack,
                                                const int* __restrict__ loc, const int* __restrict__ blkOff,
                                                const int* __restrict__ cnt,
                                                const float* __restrict__ dinv, const float* __restrict__ b1,
                                                const float* __restrict__ H0,
                                                unsigned short* __restrict__ A2) {
  const int wave = threadIdx.x >> 6, lane = threadIdx.x & 63;
  const int n = blockIdx.x * 4 + wave;  // NN divisible by 4
  const int half = lane >> 5, l32 = lane & 31;
  const int c0 = l32 * 4;               // 4 cols per lane, 32 lanes cover the row
  const int base = __builtin_amdgcn_readfirstlane(loc[n] + blkOff[n >> 8]);
  const int len = __builtin_amdgcn_readfirstlane(cnt[n]);
  float a0 = 0.f, a1 = 0.f, a2 = 0.f, a3 = 0.f;
  if (half == 0) {
    float di = dinv[n];
    float slf = di * di;
    ushort4 xv = *(const ushort4*)(xwb + (size_t)n * 128 + c0);
    a0 = b1[c0]     + slf * bf2f(xv.x);
    a1 = b1[c0 + 1] + slf * bf2f(xv.y);
    a2 = b1[c0 + 2] + slf * bf2f(xv.z);
    a3 = b1[c0 + 3] + slf * bf2f(xv.w);
  }
  float p0 = 0.f, p1 = 0.f, p2 = 0.f, p3 = 0.f;
  float q0 = 0.f, q1 = 0.f, q2 = 0.f, q3 = 0.f;
  float r0 = 0.f, r1 = 0.f, r2 = 0.f, r3 = 0.f;
  const int pairs = len >> 1;
  int j = 0;
  for (; j + 4 <= pairs; j += 4) {   // 8 edges per iteration (4 per half-wave)
    unsigned int m0 = epack[base + 2 * j + half];
    unsigned int m1 = epack[base + 2 * j + 2 + half];
    unsigned int m2 = epack[base + 2 * j + 4 + half];
    unsigned int m3 = epack[base + 2 * j + 6 + half];
    ushort4 v0 = *(const ushort4*)(xwb + (size_t)(m0 >> 15) * 128 + c0);
    ushort4 v1 = *(const ushort4*)(xwb + (size_t)(m1 >> 15) * 128 + c0);
    ushort4 v2 = *(const ushort4*)(xwb + (size_t)(m2 >> 15) * 128 + c0);
    ushort4 v3 = *(const ushort4*)(xwb + (size_t)(m3 >> 15) * 128 + c0);
    float cf0 = __uint_as_float((m0 & 0x7FFFu) << 16);
    float cf1 = __uint_as_float((m1 & 0x7FFFu) << 16);
    float cf2 = __uint_as_float((m2 & 0x7FFFu) << 16);
    float cf3 = __uint_as_float((m3 & 0x7FFFu) << 16);
    a0 += cf0 * bf2f(v0.x); a1 += cf0 * bf2f(v0.y);
    a2 += cf0 * bf2f(v0.z); a3 += cf0 * bf2f(v0.w);
    p0 += cf1 * bf2f(v1.x); p1 += cf1 * bf2f(v1.y);
    p2 += cf1 * bf2f(v1.z); p3 += cf1 * bf2f(v1.w);
    q0 += cf2 * bf2f(v2.x); q1 += cf2 * bf2f(v2.y);
    q2 += cf2 * bf2f(v2.z); q3 += cf2 * bf2f(v2.w);
    r0 += cf3 * bf2f(v3.x); r1 += cf3 * bf2f(v3.y);
    r2 += cf3 * bf2f(v3.z); r3 += cf3 * bf2f(v3.w);
  }
  for (; j < pairs; ++j) {
    unsigned int m0 = epack[base + 2 * j + half];
    ushort4 v0 = *(const ushort4*)(xwb + (size_t)(m0 >> 15) * 128 + c0);
    float cf0 = __uint_as_float((m0 & 0x7FFFu) << 16);
    a0 += cf0 * bf2f(v0.x); a1 += cf0 * bf2f(v0.y);
    a2 += cf0 * bf2f(v0.z); a3 += cf0 * bf2f(v0.w);
  }
  if ((len & 1) && half == 0) {      // odd tail edge
    unsigned int m0 = epack[base + len - 1];
    ushort4 v0 = *(const ushort4*)(xwb + (size_t)(m0 >> 15) * 128 + c0);
    float cf0 = __uint_as_float((m0 & 0x7FFFu) << 16);
    a0 += cf0 * bf2f(v0.x); a1 += cf0 * bf2f(v0.y);
    a2 += cf0 * bf2f(v0.z); a3 += cf0 * bf2f(v0.w);
  }
  a0 += (p0 + q0) + r0; a1 += (p1 + q1) + r1;
  a2 += (p2 + q2) + r2; a3 += (p3 + q3) + r3;
  a0 += __shfl_xor(a0, 32, 64);
  a1 += __shfl_xor(a1, 32, 64);
  a2 += __shfl_xor(a2, 32, 64);
  a3 += __shfl_xor(a3, 32, 64);
  if (half == 0) {
    ushort4 o; o.x = f2bf(a0); o.y = f2bf(a1); o.z = f2bf(a2); o.w = f2bf(a3);
    *(ushort4*)(A2 + (size_t)n * KG + c0) = o;
  }
  // fused: H0 f32 -> bf16 into A2 cols [128,384)
  v4f hv = *(const v4f*)(H0 + (size_t)n * 256 + lane * 4);
  ushort4 ho; ho.x = f2bf(hv.x); ho.y = f2bf(hv.y); ho.z = f2bf(hv.z); ho.w = f2bf(hv.w);
  *(ushort4*)(A2 + (size_t)n * KG + 128 + lane * 4) = ho;
}

// ---------------- gates GEMM + fused LSTM epilogue ----------------
// 512 thr / 8 waves: 2 row-halves x 4 col-quarters -> block = 128 rows x 256 cols.
// 3-buffer LDS A, B issued at phase start, counted vmcnt, 1 barrier/phase,
// setprio around MFMA clusters. XCD-chunked mapping.
__global__ __launch_bounds__(512, 4) void k_gates(const unsigned short* __restrict__ A2,
                                                  const unsigned short* __restrict__ BTk,
                                                  const float* __restrict__ biasP, const float* __restrict__ C0,
                                                  float* __restrict__ Hn, float* __restrict__ Cn,
                                                  unsigned short* __restrict__ hrelu) {
  __shared__ unsigned short As[3][128 * 64];
  const int g = blockIdx.x;
  const int xcd = g & 7, li = g >> 3;   // li 0..391
  const int xl = li >> 2, yp = li & 3;  // per-XCD: yp fastest -> A-panel L2/L3 reuse
  const int xb = xcd * 98 + xl;
  if (xb >= 782) return;
  const int t = threadIdx.x;
  const int wave = t >> 6, lane = t & 63;
  const int wr = wave >> 2, wc = wave & 3;
  const int l15 = lane & 15, l4 = lane >> 4;
  const int row0 = xb * 128;
  const int th = yp * 4 + wc;           // column th-group [th*64, +64)
  const int r_in = t >> 3, chunk = t & 7;

#define STAGE(buf, kt)                                                          \
  {                                                                             \
    _Pragma("unroll") for (int c = 0; c < 2; ++c) {                             \
      int row = c * 64 + r_in;                                                  \
      int ar = row0 + row; if (ar >= NN) ar = NN - 1;                           \
      int sc = chunk ^ (row & 7);                                               \
      gload_lds16(A2 + (size_t)ar * KG + (kt) * 64 + sc * 8,                    \
                  &As[buf][row * 64 + chunk * 8]);                              \
    }                                                                           \
  }

  const unsigned short* Bp[4];
#pragma unroll
  for (int n = 0; n < 4; ++n)
    Bp[n] = BTk + ((size_t)l4 * NCOL + (th * 64 + n * 16 + l15)) * 8;
  // k-step s lives at planes 4s..4s+3 -> offset s*4*NCOL*8 ushorts

  v4f acc[4][4];
  v4f zero = {0.f, 0.f, 0.f, 0.f};
#pragma unroll
  for (int m = 0; m < 4; ++m)
#pragma unroll
    for (int n = 0; n < 4; ++n) acc[m][n] = zero;

  STAGE(0, 0);
  STAGE(1, 1);
  asm volatile("s_waitcnt vmcnt(2)" ::: "memory");  // stage0 done; stage1 in flight
  __builtin_amdgcn_sched_barrier(0);
  asm volatile("s_barrier" ::: "memory");

#pragma unroll
  for (int kt = 0; kt < 6; ++kt) {
    const int cur = kt % 3;
    // --- issue ALL B loads for this phase FIRST (B-waits then leave stage in flight) ---
    v8s bb[2][4];
#pragma unroll
    for (int kk = 0; kk < 2; ++kk)
#pragma unroll
      for (int n = 0; n < 4; ++n) {
        const size_t poff = (size_t)((2 * kt + kk) * 4) * NCOL * 8;
        bb[kk][n] = *(const v8s*)(Bp[n] + poff);
      }
    __builtin_amdgcn_sched_barrier(0);
    if (kt < 4) STAGE((kt + 2) % 3, kt + 2);
    __builtin_amdgcn_sched_barrier(0);
#pragma unroll
    for (int kk = 0; kk < 2; ++kk) {
      v8s a[4];
#pragma unroll
      for (int m = 0; m < 4; ++m) {
        int row = wr * 64 + m * 16 + l15;
        a[m] = *(const v8s*)&As[cur][row * 64 + (((kk * 4 + l4) ^ (row & 7)) * 8)];
      }
      __builtin_amdgcn_s_setprio(1);
#pragma unroll
      for (int m = 0; m < 4; ++m)
#pragma unroll
        for (int n = 0; n < 4; ++n)
          acc[m][n] = __builtin_amdgcn_mfma_f32_16x16x32_bf16(a[m], bb[kk][n], acc[m][n], 0, 0, 0);
      __builtin_amdgcn_s_setprio(0);
    }
    if (kt < 5) {
      if (kt < 4) { asm volatile("s_waitcnt vmcnt(2)" ::: "memory"); }
      else        { asm volatile("s_waitcnt vmcnt(0)" ::: "memory"); }
      __builtin_amdgcn_sched_barrier(0);
      asm volatile("s_barrier" ::: "memory");
    }
  }
#undef STAGE

  // epilogue: n-frag index == gate (0:i 1:f 2:c 3:o); s = th*16 + l15
  const int s = th * 16 + l15;
  const int cb = th * 64 + l15;
  float bi = biasP[cb], bfv = biasP[cb + 16], bcv = biasP[cb + 32], bov = biasP[cb + 48];
#pragma unroll
  for (int m = 0; m < 4; ++m) {
#pragma unroll
    for (int r = 0; r < 4; ++r) {
      int row = row0 + wr * 64 + m * 16 + l4 * 4 + r;
      if (row < NN) {
        float I  = sigmoidf_(acc[m][0][r] + bi);
        float Fg = sigmoidf_(acc[m][1][r] + bfv);
        float T  = tanhf_(acc[m][2][r] + bcv);
        float O  = sigmoidf_(acc[m][3][r] + bov);
        size_t idx = (size_t)row * SS + s;
        float c0 = C0[idx];
        float cn = Fg * c0 + I * T;
        float hn = O * tanhf_(cn);
        Cn[idx] = cn;
        Hn[idx] = hn;
        hrelu[idx] = f2bf(hn > 0.f ? hn : 0.f);
      }
    }
  }
}

// ---------------- output linear + fused softmax ----------------
__global__ __launch_bounds__(256) void k_linsoft(const unsigned short* __restrict__ Arelu,
                                                 const unsigned short* __restrict__ WlT,
                                                 const float* __restrict__ bl, float* __restrict__ out) {
  __shared__ unsigned short As[128 * 256];
  const int t = threadIdx.x;
  const int wave = t >> 6, lane = t & 63;
  const int l15 = lane & 15, l4 = lane >> 4;
  const int row0 = blockIdx.x * 128;
#pragma unroll
  for (int c = 0; c < 16; ++c) {
    int slot = c * 256 + t;
    int row = slot >> 5, chunk = slot & 31;
    int ar = row0 + row; if (ar >= NN) ar = NN - 1;
    int sc = chunk ^ (row & 7);
    gload_lds16(Arelu + (size_t)ar * 256 + sc * 8, &As[row * 256 + chunk * 8]);
  }
  v8s bfr[8][2];
#pragma unroll
  for (int ks = 0; ks < 8; ++ks)
#pragma unroll
    for (int n = 0; n < 2; ++n)
      bfr[ks][n] = *(const v8s*)&WlT[(size_t)(n * 16 + l15) * 256 + ks * 32 + l4 * 8];
  v4f acc[2][2];
  v4f zero = {0.f, 0.f, 0.f, 0.f};
#pragma unroll
  for (int m = 0; m < 2; ++m)
#pragma unroll
    for (int n = 0; n < 2; ++n) acc[m][n] = zero;
  __syncthreads();
#pragma unroll
  for (int ks = 0; ks < 8; ++ks) {
    v8s a[2];
#pragma unroll
    for (int m = 0; m < 2; ++m) {
      int row = wave * 32 + m * 16 + l15;
      int j8 = ks * 4 + l4;
      a[m] = *(const v8s*)&As[row * 256 + ((j8 ^ (row & 7)) * 8)];
    }
#pragma unroll
    for (int m = 0; m < 2; ++m)
#pragma unroll
      for (int n = 0; n < 2; ++n)
        acc[m][n] = __builtin_amdgcn_mfma_f32_16x16x32_bf16(a[m], bfr[ks][n], acc[m][n], 0, 0, 0);
  }
  float b0 = bl[l15], b1v = bl[16 + l15];
#pragma unroll
  for (int m = 0; m < 2; ++m) {
#pragma unroll
    for (int r = 0; r < 4; ++r) {
      int row = row0 + wave * 32 + m * 16 + l4 * 4 + r;
      float v0 = acc[m][0][r] + b0;
      float v1 = acc[m][1][r] + b1v;
      float mx = fmaxf(v0, v1);
#pragma unroll
      for (int d = 1; d < 16; d <<= 1) mx = fmaxf(mx, __shfl_xor(mx, d, 64));
      float e0 = __expf(v0 - mx), e1 = __expf(v1 - mx);
      float sm = e0 + e1;
#pragma unroll
      for (int d = 1; d < 16; d <<= 1) sm += __shfl_xor(sm, d, 64);
      if (row < NN) {
        out[(size_t)row * 32 + l15] = e0 / sm;
        out[(size_t)row * 32 + 16 + l15] = e1 / sm;
      }
    }
  }
}

extern "C" void kernel_launch(void* const* d_in, const int* in_sizes, int n_in,
                              void* d_out, int out_size, void* d_ws, size_t ws_size,
                              hipStream_t stream) {
  (void)in_sizes; (void)n_in; (void)out_size; (void)ws_size;
  const float* x   = (const float*)d_in[0];
  const int*   ei  = (const int*)d_in[1];
  const float* ew  = (const float*)d_in[2];
  const float* H0  = (const float*)d_in[3];
  const float* C0  = (const float*)d_in[4];
  const float* W1  = (const float*)d_in[5];
  const float* b1  = (const float*)d_in[6];
  const float* Wi  = (const float*)d_in[7];
  const float* Ti  = (const float*)d_in[8];
  const float* bci = (const float*)d_in[9];
  const float* bii = (const float*)d_in[10];
  const float* Wf  = (const float*)d_in[11];
  const float* Tf  = (const float*)d_in[12];
  const float* bcf = (const float*)d_in[13];
  const float* bif = (const float*)d_in[14];
  const float* Wc  = (const float*)d_in[15];
  const float* Tc  = (const float*)d_in[16];
  const float* bcc = (const float*)d_in[17];
  const float* bic = (const float*)d_in[18];
  const float* Wo  = (const float*)d_in[19];
  const float* To  = (const float*)d_in[20];
  const float* bco = (const float*)d_in[21];
  const float* bio = (const float*)d_in[22];
  const float* Wl  = (const float*)d_in[23];
  const float* bl  = (const float*)d_in[24];

  const int* srcI = ei;
  const int* dstI = ei + EE;

  char* ws = (char*)d_ws;
  size_t off = 0;
  auto carve = [&](size_t bytes) -> char* {
    char* p = ws + off;
    off += (bytes + 255) & ~(size_t)255;
    return p;
  };
  unsigned long long* degcnt = (unsigned long long*)carve((size_t)NN * 8);
  float* dinv          = (float*)carve((size_t)NN * 4);
  int*   loc           = (int*)carve((size_t)NN * 4);
  int*   cnt32         = (int*)carve((size_t)NN * 4);
  int*   blkSum        = (int*)carve(512 * 4);
  int*   blkOff        = (int*)carve(512 * 4);
  unsigned short* posA = (unsigned short*)carve((size_t)EE * 2);
  unsigned int* epack  = (unsigned int*)carve((size_t)EE * 4);
  unsigned short* W1T  = (unsigned short*)carve((size_t)FF * FF * 2);
  unsigned short* xwb  = (unsigned short*)carve((size_t)NN * FF * 2);
  unsigned short* A2   = (unsigned short*)carve((size_t)NN * KG * 2);
  unsigned short* BTk  = (unsigned short*)carve((size_t)NCOL * KG * 2);
  float* biasP         = (float*)carve((size_t)NCOL * 4);
  unsigned short* WlT  = (unsigned short*)carve((size_t)CC * SS * 2);
  unsigned short* hrelu = (unsigned short*)carve((size_t)NN * SS * 2);

  float* outSm = (float*)d_out;
  float* HnO = outSm + (size_t)NN * CC;
  float* CnO = HnO + (size_t)NN * SS;

  const int NB = (NN + 255) / 256;  // 391

  hipMemsetAsync(degcnt, 0, (size_t)NN * 8, stream);
  // fused: degree atomics + all weight packs
  k_pre<<<6250 + 1636, 256, 0, stream>>>(dstI, ew, degcnt, posA,
                                         W1, W1T, Wi, Wf, Wc, Wo, Ti, Tf, Tc, To, BTk,
                                         bci, bcf, bcc, bco, bii, bif, bic, bio, biasP,
                                         Wl, WlT);
  k_scan1<<<NB, 256, 0, stream>>>(degcnt, loc, cnt32, blkSum, dinv);
  k_scan2<<<1, 512, 0, stream>>>(blkSum, blkOff, NB);
  // fused: CSR fill + GEMM1
  k_mid<<<6250 + 782, 256, 0, stream>>>(srcI, dstI, ew, dinv, loc, blkOff, posA, epack,
                                        x, W1T, xwb);
  k_gather<<<25000, 256, 0, stream>>>(xwb, epack, loc, blkOff, cnt32, dinv, b1, H0, A2);
  k_gates<<<3136, 512, 0, stream>>>(A2, BTk, biasP, C0, HnO, CnO, hrelu);
  k_linsoft<<<782, 256, 0, stream>>>(hrelu, WlT, bl, outSm);
}